// Round 14
// baseline (104.238 us; speedup 1.0000x reference)
//
#include <hip/hip_runtime.h>
#include <hip/hip_bf16.h>

// ---------------------------------------------------------------------------
// Def_DownSampling, round 14.
//  * gaus_w identical per (oc,ic) => gaussian path uses channel-summed field.
//  * conv3+avgpool folded to stride-2 4^3 conv (W4), exact algebra.
//  * D via bf16 MFMA; Dsum kept fp32 (packed pk_fma dot) for the grid path.
//  * R13: k_sample TLP (8192 blocks) — worked.
//  * R14: conv grid was structurally capped at 4 blocks/CU (1024 x 64-pos
//    blocks). Now 2048 x 128-thr (2-wave) blocks, 1-ic weight LDS dbuf
//    (16.8 KB -> 8 blocks/CU resident); dp accumulated as float4v (pk_fma).
// Outputs: y (2,32,32,32,32) | D (2,32,32,32,32) | grid-mean (2,32,32,32,3)
// ---------------------------------------------------------------------------

#define XN 64
#define DN 32
#define C  32
#define XVOL (XN * XN * XN)   // 262144
#define DVOL (DN * DN * DN)   // 32768

typedef __attribute__((ext_vector_type(8))) short short8v;
typedef __attribute__((ext_vector_type(4))) float float4v;

struct __attribute__((packed, aligned(4))) f4u { float4v v; };
struct __attribute__((packed, aligned(4))) s8u { short8v v; };

static __device__ __forceinline__ short f2bf(float f) {
    union { float f; unsigned u; } v; v.f = f;
    unsigned r = (v.u + 0x7fffu + ((v.u >> 16) & 1u)) >> 16;   // RNE
    return (short)r;
}

static __device__ __forceinline__ unsigned pk2(float a, float b) {
    __hip_bfloat162 h = __float22bfloat162_rn(float2{a, b});
    union { __hip_bfloat162 h2; unsigned u; } cv; cv.h2 = h;
    return cv.u;
}

// shifted-masked taps: out[c] = mc*ld[c] + ml*ld[c-1] + mr*ld[c+1]
static __device__ __forceinline__ float4v shmask(float4v ld, float c, float l, float r) {
    float4v o;
    o[0] = fmaf(r, ld[1], c * ld[0]);
    o[1] = fmaf(l, ld[0], fmaf(r, ld[2], c * ld[1]));
    o[2] = fmaf(l, ld[1], fmaf(r, ld[3], c * ld[2]));
    o[3] = fmaf(l, ld[2], c * ld[3]);
    return o;
}

// W4[ic][u][oc] = (1/8) sum_{s in {0,1}^3} conv_w[oc][ic][u-s]
static __device__ __forceinline__ float w4val(const float* __restrict__ conv_w,
                                              int ic, int u, int oc) {
    int uz = u >> 4, uy = (u >> 2) & 3, ux = u & 3;
    float s = 0.f;
    #pragma unroll
    for (int sz = 0; sz < 2; ++sz) {
        int tz = uz - sz; if (tz < 0 || tz > 2) continue;
        #pragma unroll
        for (int sy = 0; sy < 2; ++sy) {
            int ty = uy - sy; if (ty < 0 || ty > 2) continue;
            #pragma unroll
            for (int sx = 0; sx < 2; ++sx) {
                int tx = ux - sx; if (tx < 0 || tx > 2) continue;
                s += conv_w[(oc * C + ic) * 27 + tz * 9 + ty * 3 + tx];
            }
        }
    }
    return 0.125f * s;
}

// ---- K0: blocks 0..255 pack A-fragments (bf16) + biassum;
//          blocks 256..511 compute wsum[k] = sum_oc W4[k][oc] via shfl tree.
__global__ __launch_bounds__(256) void k_prep(const float* __restrict__ conv_w,
                                              const float* __restrict__ conv_b,
                                              unsigned short* __restrict__ wfrag,
                                              float* __restrict__ wsum) {
    int bid = blockIdx.x;
    int tid = threadIdx.x;
    if (bid < 256) {
        int i = bid * 256 + tid;                // 65536
        int e = i & 7;
        int l = (i >> 3) & 63;
        int sf = i >> 9;
        int f = sf & 1, step = sf >> 1;
        int oc = f * 16 + (l & 15);
        int k = step * 32 + ((l >> 4) * 8 + e);
        float v = w4val(conv_w, k >> 6, k & 63, oc);
        wfrag[i] = (unsigned short)f2bf(v);
        if (i == 0) {
            float s = 0.f;
            for (int o = 0; o < C; ++o) s += conv_b[o];
            wsum[2048] = s;
        }
    } else {
        int i2 = (bid - 256) * 256 + tid;       // 65536 = 2048 k x 32 oc
        int oc = tid & 31;
        int kk = i2 >> 5;
        float v = w4val(conv_w, kk >> 6, kk & 63, oc);
        v += __shfl_xor(v, 1, 64);
        v += __shfl_xor(v, 2, 64);
        v += __shfl_xor(v, 4, 64);
        v += __shfl_xor(v, 8, 64);
        v += __shfl_xor(v, 16, 64);
        if (oc == 0) wsum[kk] = v;
    }
}

// ---- K1: MFMA conv. 2048 blocks x 128 thr (2 waves).
// Wave w = output (zt, yt*2+w, xt*16+col), all 32 oc.
// Weights: LDS double-buffer, 1 ic (4160 B, chunk-padded) per stage.
__global__ __launch_bounds__(128) void k_conv_mfma(
        const float* __restrict__ x, const unsigned short* __restrict__ wfrag,
        const float* __restrict__ wsum, const float* __restrict__ bias,
        float* __restrict__ Dout, float* __restrict__ Dsum) {
    __shared__ float wsl[2112];
    __shared__ char wbuf[2 * 4160];
    int tid = threadIdx.x;
    for (int i = tid; i < 513; i += 128)
        *(float4v*)&wsl[i * 4] = *(const float4v*)&wsum[i * 4];

    int bid = blockIdx.x;
    int wid = (bid & 7) * 256 + (bid >> 3);      // XCD-chunked swizzle (2048%8==0)
    int xt = wid & 1;
    int yt = (wid >> 1) & 15;
    int zt = (wid >> 5) & 31;
    int b  = wid >> 10;
    int w = tid >> 6, lane = tid & 63;
    int col = lane & 15, g = lane >> 4;
    int pz = zt, py = yt * 2 + w, px = xt * 16 + col;

    const char* xb = (const char*)(x + (size_t)b * C * XVOL);
    const char* wfb = (const char*)wfrag;

    // stage mapping: thread t loads 32 B of this ic's 4096 B at t*32;
    // chunk = t>>5 (1024 B each, stored at 1040 B stride), off = (t&31)*32.
    int sdst = (tid >> 5) * 1040 + (tid & 31) * 32;

    int gxb = 2 * px - 1;
    int gxc = min(max(gxb, 0), XN - 4);
    int s = gxc - gxb;
    int offb[4];
    float mc[4], ml[4], mr[4];
    #pragma unroll
    for (int h = 0; h < 2; ++h)
    #pragma unroll
    for (int rs = 0; rs < 2; ++rs) {
        int gz = 2 * pz - 1 + 2 * h + (g >> 1);
        int gy = 2 * py - 1 + (g & 1) * 2 + rs;
        bool rv = (unsigned)gz < (unsigned)XN && (unsigned)gy < (unsigned)XN;
        int gzc = min(max(gz, 0), XN - 1);
        int gyc = min(max(gy, 0), XN - 1);
        int idx = h * 2 + rs;
        offb[idx] = ((gzc * XN + gyc) * XN + gxc) * 4;
        mc[idx] = (rv && s == 0)  ? 1.f : 0.f;
        ml[idx] = (rv && s == 1)  ? 1.f : 0.f;
        mr[idx] = (rv && s == -1) ? 1.f : 0.f;
    }

    float4v acc0 = {0.f, 0.f, 0.f, 0.f};
    float4v acc1 = {0.f, 0.f, 0.f, 0.f};
    float4v dpv = {0.f, 0.f, 0.f, 0.f};
    float4v tA[4], tB[4];
    short8v sg0, sg1;

#define LOADT(T, j) do {                                                     \
    const char* xp = xb + (size_t)(j) * (XVOL * 4);                          \
    _Pragma("unroll")                                                        \
    for (int i5 = 0; i5 < 4; ++i5)                                           \
        T[i5] = ((const f4u*)(xp + offb[i5]))->v;                            \
} while (0)

#define STAGE_LOAD(st) do {                                                  \
    const char* wp = wfb + (size_t)(st) * 4096 + tid * 32;                   \
    sg0 = ((const s8u*)(wp))->v;                                             \
    sg1 = ((const s8u*)(wp + 16))->v;                                        \
} while (0)

#define STAGE_WRITE(bf) do {                                                 \
    *(short8v*)(wbuf + (bf) * 4160 + sdst) = sg0;                            \
    *(short8v*)(wbuf + (bf) * 4160 + sdst + 16) = sg1;                       \
} while (0)

#define COMPT(T, bf, j) do {                                                 \
    _Pragma("unroll")                                                        \
    for (int h5 = 0; h5 < 2; ++h5) {                                         \
        float4v r0 = shmask(T[h5 * 2],     mc[h5 * 2],     ml[h5 * 2],     mr[h5 * 2]);     \
        float4v r1 = shmask(T[h5 * 2 + 1], mc[h5 * 2 + 1], ml[h5 * 2 + 1], mr[h5 * 2 + 1]); \
        const float4v wlo = *(const float4v*)&wsl[((j) * 2 + h5) * 32 + g * 8];     \
        const float4v whi = *(const float4v*)&wsl[((j) * 2 + h5) * 32 + g * 8 + 4]; \
        dpv += wlo * r0;                                                     \
        dpv += whi * r1;                                                     \
        union { short8v s; unsigned u[4]; } Bv;                              \
        Bv.u[0] = pk2(r0[0], r0[1]); Bv.u[1] = pk2(r0[2], r0[3]);            \
        Bv.u[2] = pk2(r1[0], r1[1]); Bv.u[3] = pk2(r1[2], r1[3]);            \
        const char* wl = wbuf + (bf) * 4160 + lane * 16;                     \
        short8v w0 = *(const short8v*)(wl + (h5 * 2) * 1040);                \
        short8v w1 = *(const short8v*)(wl + (h5 * 2 + 1) * 1040);            \
        acc0 = __builtin_amdgcn_mfma_f32_16x16x32_bf16(w0, Bv.s, acc0, 0, 0, 0); \
        acc1 = __builtin_amdgcn_mfma_f32_16x16x32_bf16(w1, Bv.s, acc1, 0, 0, 0); \
    }                                                                        \
} while (0)

    STAGE_LOAD(0);
    STAGE_WRITE(0);
    LOADT(tA, 0);
    LOADT(tB, 1);
    __syncthreads();

    for (int st = 0; st < C; ++st) {
        int cur = st & 1;
        if (st < C - 1) STAGE_LOAD(st + 1);       // issue-early (T14)
        if (cur == 0) {
            COMPT(tA, cur, st);
            if (st + 2 < C) LOADT(tA, st + 2);
        } else {
            COMPT(tB, cur, st);
            if (st + 2 < C) LOADT(tB, st + 2);
        }
        if (st < C - 1) {
            STAGE_WRITE(cur ^ 1);                 // write-late
            __syncthreads();
        }
    }

#undef LOADT
#undef STAGE_LOAD
#undef STAGE_WRITE
#undef COMPT

    float dp = (dpv[0] + dpv[1]) + (dpv[2] + dpv[3]);
    dp += __shfl_xor(dp, 16, 64);
    dp += __shfl_xor(dp, 32, 64);

    int sp = pz * (DN * DN) + py * DN + px;
    float4v b0 = *(const float4v*)&bias[g * 4];
    float4v b1 = *(const float4v*)&bias[16 + g * 4];
    #pragma unroll
    for (int r = 0; r < 4; ++r) {
        int oc0 = g * 4 + r;
        int oc1 = 16 + g * 4 + r;
        Dout[(size_t)(b * C + oc0) * DVOL + sp] = acc0[r] + b0[r];
        Dout[(size_t)(b * C + oc1) * DVOL + sp] = acc1[r] + b1[r];
    }
    if (g == 0)
        Dsum[b * DVOL + sp] = dp + wsl[2048];
}

// ---- K2: 5^3 gaussian, LDS-staged. Block = (4z x 8y x 8x), 256 blocks.
__global__ __launch_bounds__(256) void k_gauss(const float* __restrict__ Dsum,
                                               const float* __restrict__ gaus_w,
                                               float* __restrict__ filt,
                                               float* __restrict__ outg) {
    __shared__ float tg[8 * 12 * 12];   // 1152
    __shared__ float gk[125];
    int bid = blockIdx.x;
    int xt = bid & 3, yt = (bid >> 2) & 3, zt = (bid >> 4) & 7, b = bid >> 7;
    int tid = threadIdx.x;
    if (tid < 125) gk[tid] = gaus_w[tid];   // replicated kernel: [0][0] slice
    const float* Ds = Dsum + b * DVOL;
    for (int i = tid; i < 1152; i += 256) {
        int lx = i % 12; int r = i / 12; int ly = r % 12; int lz = r / 12;
        int gz = zt * 4 - 2 + lz, gy = yt * 8 - 2 + ly, gx = xt * 8 - 2 + lx;
        float v = 0.f;
        if ((unsigned)gz < DN && (unsigned)gy < DN && (unsigned)gx < DN)
            v = Ds[(gz * DN + gy) * DN + gx];
        tg[i] = v;
    }
    __syncthreads();
    int px = tid & 7, py = (tid >> 3) & 7, pz = tid >> 6;
    const float inv31 = 1.f / 31.f;
    float zb = (float)(zt * 4 + pz - 2);
    float yb = (float)(yt * 8 + py - 2);
    float xb = (float)(xt * 8 + px - 2);
    float p = 0.f, a0 = 0.f, a1 = 0.f, a2 = 0.f;
    for (int tz = 0; tz < 5; ++tz)
    for (int ty = 0; ty < 5; ++ty) {
        int base = ((pz + tz) * 12 + py + ty) * 12 + px;
        #pragma unroll
        for (int tx = 0; tx < 5; ++tx) {
            float g = gk[tz * 25 + ty * 5 + tx];
            float v = g * tg[base + tx];
            p += v;
            a0 = fmaf(v, (zb + (float)tz) * inv31, a0);
            a1 = fmaf(v, (yb + (float)ty) * inv31, a1);
            a2 = fmaf(v, (xb + (float)tx) * inv31, a2);
        }
    }
    float denom = p + 1e-6f;
    float f0 = fminf(fmaxf(a0 / denom * 2.f - 1.f, -1.f), 1.f);
    float f1 = fminf(fmaxf(a1 / denom * 2.f - 1.f, -1.f), 1.f);
    float f2 = fminf(fmaxf(a2 / denom * 2.f - 1.f, -1.f), 1.f);
    int sp = ((zt * 4 + pz) * DN + yt * 8 + py) * DN + xt * 8 + px;
    filt[(b * 3 + 0) * DVOL + sp] = f0;
    filt[(b * 3 + 1) * DVOL + sp] = f1;
    filt[(b * 3 + 2) * DVOL + sp] = f2;
    outg[(size_t)(b * DVOL + sp) * 3 + 0] = f0;
    outg[(size_t)(b * DVOL + sp) * 3 + 1] = f1;
    outg[(size_t)(b * DVOL + sp) * 3 + 2] = f2;
}

// ---- K3: trilinear grid sample. 8192 blocks x 128 thr; tile (2z,4y,16x),
// 2 channels per block -> 64 waves/CU oversubscription (TLP latency hiding).
__global__ __launch_bounds__(128) void k_sample(const float* __restrict__ x,
                                                const float* __restrict__ filt,
                                                float* __restrict__ y) {
    int bid = blockIdx.x;
    int wid = (bid & 7) * 1024 + (bid >> 3);  // 8192%8==0, bijective chunk
    int xt = wid & 1;
    int yt = (wid >> 1) & 7;
    int zt = (wid >> 4) & 15;
    int cgrp = (wid >> 8) & 15;               // 16 groups x 2 channels
    int b  = wid >> 12;
    int tid = threadIdx.x;
    int px = tid & 15, py = (tid >> 4) & 3, pz = tid >> 6;
    int sp = ((zt * 2 + pz) * DN + yt * 4 + py) * DN + xt * 16 + px;
    const float* fb = filt + b * 3 * DVOL;
    float g0 = fb[sp], g1 = fb[DVOL + sp], g2 = fb[2 * DVOL + sp];

    float ix = ((g0 + 1.0f) * (float)XN - 1.0f) * 0.5f;
    float iy = ((g1 + 1.0f) * (float)XN - 1.0f) * 0.5f;
    float iz = ((g2 + 1.0f) * (float)XN - 1.0f) * 0.5f;
    float x0f = floorf(ix), y0f = floorf(iy), z0f = floorf(iz);
    float wx = ix - x0f, wyf = iy - y0f, wz = iz - z0f;
    int x0 = (int)x0f, y0i = (int)y0f, z0 = (int)z0f;

    int offs[8];
    float wts[8];
    #pragma unroll
    for (int t = 0; t < 8; ++t) {
        int dz = t >> 2, dy = (t >> 1) & 1, dx = t & 1;
        int zc = z0 + dz, yc = y0i + dy, xc = x0 + dx;
        bool valid = (unsigned)zc < (unsigned)XN && (unsigned)yc < (unsigned)XN &&
                     (unsigned)xc < (unsigned)XN;
        int zcl = min(max(zc, 0), XN - 1);
        int ycl = min(max(yc, 0), XN - 1);
        int xcl = min(max(xc, 0), XN - 1);
        offs[t] = zcl * (XN * XN) + ycl * XN + xcl;
        float w = (dz ? wz : 1.f - wz) * (dy ? wyf : 1.f - wyf) * (dx ? wx : 1.f - wx);
        wts[t] = valid ? w : 0.f;
    }

    const float* xc0 = x + (size_t)(b * C + cgrp * 2) * XVOL;
    float t0[8], t1[8];
    #pragma unroll
    for (int k = 0; k < 8; ++k) t0[k] = xc0[offs[k]];
    #pragma unroll
    for (int k = 0; k < 8; ++k) t1[k] = xc0[XVOL + offs[k]];

    float a0 = 0.f, a1 = 0.f;
    #pragma unroll
    for (int k = 0; k < 8; ++k) a0 = fmaf(wts[k], t0[k], a0);
    #pragma unroll
    for (int k = 0; k < 8; ++k) a1 = fmaf(wts[k], t1[k], a1);
    y[(size_t)(b * C + cgrp * 2 + 0) * DVOL + sp] = a0;
    y[(size_t)(b * C + cgrp * 2 + 1) * DVOL + sp] = a1;
}

extern "C" void kernel_launch(void* const* d_in, const int* in_sizes, int n_in,
                              void* d_out, int out_size, void* d_ws, size_t ws_size,
                              hipStream_t stream) {
    const float* x      = (const float*)d_in[0];
    const float* conv_w = (const float*)d_in[1];
    const float* conv_b = (const float*)d_in[2];
    const float* gaus_w = (const float*)d_in[3];

    float* out = (float*)d_out;
    float* y_out = out;
    float* D_out = out + (size_t)2097152;
    float* g_out = out + (size_t)4194304;

    float* ws   = (float*)d_ws;
    float* Dsum = ws;                         // 65536 f
    float* filt = ws + 65536;                 // 196608 f
    float* wsum = ws + 262144;                // 2049 f (+pad to 2112)
    unsigned short* wfrag = (unsigned short*)(ws + 264256);  // 65536 u16

    k_prep<<<dim3(512), dim3(256), 0, stream>>>(conv_w, conv_b, wfrag, wsum);
    k_conv_mfma<<<dim3(2048), dim3(128), 0, stream>>>(x, wfrag, wsum, conv_b,
                                                      D_out, Dsum);
    k_gauss<<<dim3(256), dim3(256), 0, stream>>>(Dsum, gaus_w, filt, g_out);
    k_sample<<<dim3(8192), dim3(128), 0, stream>>>(x, filt, y_out);
    (void)in_sizes; (void)n_in; (void)out_size; (void)ws_size;
}

// Round 15
// 87.582 us; speedup vs baseline: 1.1902x; 1.1902x over previous
//
#include <hip/hip_runtime.h>
#include <hip/hip_bf16.h>

// ---------------------------------------------------------------------------
// Def_DownSampling, round 15.
//  * gaus_w identical per (oc,ic) => gaussian path uses channel-summed field.
//  * conv3+avgpool folded to stride-2 4^3 conv (W4), exact algebra.
//  * D via bf16 MFMA; Dsum kept fp32 (packed pk_fma dot) for the grid path.
//  * R15: revert R14's regression (32B-stride LDS staging -> 4-way bank
//    conflicts, 2x barriers). Conv = R13's proven structure (1024x256,
//    2-ic dbuf, 16B-stride staging, 0 conflicts) + dpv packed accumulate
//    (the one R14 change that was validated: -12% VALU, absmax 0.0371).
// Outputs: y (2,32,32,32,32) | D (2,32,32,32,32) | grid-mean (2,32,32,32,3)
// ---------------------------------------------------------------------------

#define XN 64
#define DN 32
#define C  32
#define XVOL (XN * XN * XN)   // 262144
#define DVOL (DN * DN * DN)   // 32768

typedef __attribute__((ext_vector_type(8))) short short8v;
typedef __attribute__((ext_vector_type(4))) float float4v;

struct __attribute__((packed, aligned(4))) f4u { float4v v; };
struct __attribute__((packed, aligned(4))) s8u { short8v v; };

static __device__ __forceinline__ short f2bf(float f) {
    union { float f; unsigned u; } v; v.f = f;
    unsigned r = (v.u + 0x7fffu + ((v.u >> 16) & 1u)) >> 16;   // RNE
    return (short)r;
}

static __device__ __forceinline__ unsigned pk2(float a, float b) {
    __hip_bfloat162 h = __float22bfloat162_rn(float2{a, b});
    union { __hip_bfloat162 h2; unsigned u; } cv; cv.h2 = h;
    return cv.u;
}

// shifted-masked taps: out[c] = mc*ld[c] + ml*ld[c-1] + mr*ld[c+1]
static __device__ __forceinline__ float4v shmask(float4v ld, float c, float l, float r) {
    float4v o;
    o[0] = fmaf(r, ld[1], c * ld[0]);
    o[1] = fmaf(l, ld[0], fmaf(r, ld[2], c * ld[1]));
    o[2] = fmaf(l, ld[1], fmaf(r, ld[3], c * ld[2]));
    o[3] = fmaf(l, ld[2], c * ld[3]);
    return o;
}

// W4[ic][u][oc] = (1/8) sum_{s in {0,1}^3} conv_w[oc][ic][u-s]
static __device__ __forceinline__ float w4val(const float* __restrict__ conv_w,
                                              int ic, int u, int oc) {
    int uz = u >> 4, uy = (u >> 2) & 3, ux = u & 3;
    float s = 0.f;
    #pragma unroll
    for (int sz = 0; sz < 2; ++sz) {
        int tz = uz - sz; if (tz < 0 || tz > 2) continue;
        #pragma unroll
        for (int sy = 0; sy < 2; ++sy) {
            int ty = uy - sy; if (ty < 0 || ty > 2) continue;
            #pragma unroll
            for (int sx = 0; sx < 2; ++sx) {
                int tx = ux - sx; if (tx < 0 || tx > 2) continue;
                s += conv_w[(oc * C + ic) * 27 + tz * 9 + ty * 3 + tx];
            }
        }
    }
    return 0.125f * s;
}

// ---- K0: blocks 0..255 pack A-fragments (bf16) + biassum;
//          blocks 256..511 compute wsum[k] = sum_oc W4[k][oc] via shfl tree.
__global__ __launch_bounds__(256) void k_prep(const float* __restrict__ conv_w,
                                              const float* __restrict__ conv_b,
                                              unsigned short* __restrict__ wfrag,
                                              float* __restrict__ wsum) {
    int bid = blockIdx.x;
    int tid = threadIdx.x;
    if (bid < 256) {
        int i = bid * 256 + tid;                // 65536
        int e = i & 7;
        int l = (i >> 3) & 63;
        int sf = i >> 9;
        int f = sf & 1, step = sf >> 1;
        int oc = f * 16 + (l & 15);
        int k = step * 32 + ((l >> 4) * 8 + e);
        float v = w4val(conv_w, k >> 6, k & 63, oc);
        wfrag[i] = (unsigned short)f2bf(v);
        if (i == 0) {
            float s = 0.f;
            for (int o = 0; o < C; ++o) s += conv_b[o];
            wsum[2048] = s;
        }
    } else {
        int i2 = (bid - 256) * 256 + tid;       // 65536 = 2048 k x 32 oc
        int oc = tid & 31;
        int kk = i2 >> 5;
        float v = w4val(conv_w, kk >> 6, kk & 63, oc);
        v += __shfl_xor(v, 1, 64);
        v += __shfl_xor(v, 2, 64);
        v += __shfl_xor(v, 4, 64);
        v += __shfl_xor(v, 8, 64);
        v += __shfl_xor(v, 16, 64);
        if (oc == 0) wsum[kk] = v;
    }
}

// ---- K1: MFMA conv. 1024 blocks x 256 thr (4 waves).
// Wave w = output (zt*2+(w>>1), yt*2+(w&1), xt*16 + col), all 32 oc.
// Weights: LDS double-buffer, 2 ic (8 KB) per stage, all 4 waves share.
// 16B-stride staging (R11 pattern, measured 0 bank conflicts).
__global__ __launch_bounds__(256) void k_conv_mfma(
        const float* __restrict__ x, const unsigned short* __restrict__ wfrag,
        const float* __restrict__ wsum, const float* __restrict__ bias,
        float* __restrict__ Dout, float* __restrict__ Dsum) {
    __shared__ float wsl[2112];
    __shared__ char wbuf[2 * 8320];
    int tid = threadIdx.x;
    for (int i = tid; i < 513; i += 256)
        *(float4v*)&wsl[i * 4] = *(const float4v*)&wsum[i * 4];

    int bid = blockIdx.x;
    int wid = (bid & 7) * 128 + (bid >> 3);      // XCD-chunked swizzle (1024%8==0)
    int xt = wid & 1;
    int yt = (wid >> 1) & 15;
    int zt = (wid >> 5) & 15;
    int b  = wid >> 9;
    int w = tid >> 6, lane = tid & 63;
    int col = lane & 15, g = lane >> 4;
    int pz = zt * 2 + (w >> 1), py = yt * 2 + (w & 1), px = xt * 16 + col;

    const char* xb = (const char*)(x + (size_t)b * C * XVOL);
    const char* wfb = (const char*)wfrag;

    int sdst = (tid >> 6) * 1040 + (tid & 63) * 16;

    int gxb = 2 * px - 1;
    int gxc = min(max(gxb, 0), XN - 4);
    int s = gxc - gxb;
    int offb[4];
    float mc[4], ml[4], mr[4];
    #pragma unroll
    for (int h = 0; h < 2; ++h)
    #pragma unroll
    for (int rs = 0; rs < 2; ++rs) {
        int gz = 2 * pz - 1 + 2 * h + (g >> 1);
        int gy = 2 * py - 1 + (g & 1) * 2 + rs;
        bool rv = (unsigned)gz < (unsigned)XN && (unsigned)gy < (unsigned)XN;
        int gzc = min(max(gz, 0), XN - 1);
        int gyc = min(max(gy, 0), XN - 1);
        int idx = h * 2 + rs;
        offb[idx] = ((gzc * XN + gyc) * XN + gxc) * 4;
        mc[idx] = (rv && s == 0)  ? 1.f : 0.f;
        ml[idx] = (rv && s == 1)  ? 1.f : 0.f;
        mr[idx] = (rv && s == -1) ? 1.f : 0.f;
    }

    float4v acc0 = {0.f, 0.f, 0.f, 0.f};
    float4v acc1 = {0.f, 0.f, 0.f, 0.f};
    float4v dpv = {0.f, 0.f, 0.f, 0.f};
    float4v tA[4], tB[4];
    short8v sg0, sg1;

#define LOADT(T, j) do {                                                     \
    const char* xp = xb + (size_t)(j) * (XVOL * 4);                          \
    _Pragma("unroll")                                                        \
    for (int i5 = 0; i5 < 4; ++i5)                                           \
        T[i5] = ((const f4u*)(xp + offb[i5]))->v;                            \
} while (0)

#define STAGE_LOAD(st) do {                                                  \
    const char* wp = wfb + (size_t)(st) * 8192 + tid * 16;                   \
    sg0 = ((const s8u*)(wp))->v;                                             \
    sg1 = ((const s8u*)(wp + 4096))->v;                                      \
} while (0)

#define STAGE_WRITE(bf) do {                                                 \
    *(short8v*)(wbuf + (bf) * 8320 + sdst) = sg0;                            \
    *(short8v*)(wbuf + (bf) * 8320 + 4160 + sdst) = sg1;                     \
} while (0)

#define COMPT(T, bf, icL, j) do {                                            \
    _Pragma("unroll")                                                        \
    for (int h5 = 0; h5 < 2; ++h5) {                                         \
        float4v r0 = shmask(T[h5 * 2],     mc[h5 * 2],     ml[h5 * 2],     mr[h5 * 2]);     \
        float4v r1 = shmask(T[h5 * 2 + 1], mc[h5 * 2 + 1], ml[h5 * 2 + 1], mr[h5 * 2 + 1]); \
        const float4v wlo = *(const float4v*)&wsl[((j) * 2 + h5) * 32 + g * 8];     \
        const float4v whi = *(const float4v*)&wsl[((j) * 2 + h5) * 32 + g * 8 + 4]; \
        dpv += wlo * r0;                                                     \
        dpv += whi * r1;                                                     \
        union { short8v s; unsigned u[4]; } Bv;                              \
        Bv.u[0] = pk2(r0[0], r0[1]); Bv.u[1] = pk2(r0[2], r0[3]);            \
        Bv.u[2] = pk2(r1[0], r1[1]); Bv.u[3] = pk2(r1[2], r1[3]);            \
        const char* wl = wbuf + (bf) * 8320 + (icL) * 4160 + lane * 16;      \
        short8v w0 = *(const short8v*)(wl + (h5 * 2) * 1040);                \
        short8v w1 = *(const short8v*)(wl + (h5 * 2 + 1) * 1040);            \
        acc0 = __builtin_amdgcn_mfma_f32_16x16x32_bf16(w0, Bv.s, acc0, 0, 0, 0); \
        acc1 = __builtin_amdgcn_mfma_f32_16x16x32_bf16(w1, Bv.s, acc1, 0, 0, 0); \
    }                                                                        \
} while (0)

    STAGE_LOAD(0);
    STAGE_WRITE(0);
    LOADT(tA, 0);
    LOADT(tB, 1);
    __syncthreads();

    for (int st = 0; st < 16; ++st) {
        int cur = st & 1;
        if (st < 15) STAGE_LOAD(st + 1);          // issue-early (T14)
        int ic = st * 2;
        COMPT(tA, cur, 0, ic);
        if (ic + 2 < C) LOADT(tA, ic + 2);
        COMPT(tB, cur, 1, ic + 1);
        if (ic + 3 < C) LOADT(tB, ic + 3);
        if (st < 15) {
            STAGE_WRITE(cur ^ 1);                 // write-late
            __syncthreads();
        }
    }

#undef LOADT
#undef STAGE_LOAD
#undef STAGE_WRITE
#undef COMPT

    float dp = (dpv[0] + dpv[1]) + (dpv[2] + dpv[3]);
    dp += __shfl_xor(dp, 16, 64);
    dp += __shfl_xor(dp, 32, 64);

    int sp = pz * (DN * DN) + py * DN + px;
    float4v b0 = *(const float4v*)&bias[g * 4];
    float4v b1 = *(const float4v*)&bias[16 + g * 4];
    #pragma unroll
    for (int r = 0; r < 4; ++r) {
        int oc0 = g * 4 + r;
        int oc1 = 16 + g * 4 + r;
        Dout[(size_t)(b * C + oc0) * DVOL + sp] = acc0[r] + b0[r];
        Dout[(size_t)(b * C + oc1) * DVOL + sp] = acc1[r] + b1[r];
    }
    if (g == 0)
        Dsum[b * DVOL + sp] = dp + wsl[2048];
}

// ---- K2: 5^3 gaussian, LDS-staged. Block = (4z x 8y x 8x), 256 blocks.
__global__ __launch_bounds__(256) void k_gauss(const float* __restrict__ Dsum,
                                               const float* __restrict__ gaus_w,
                                               float* __restrict__ filt,
                                               float* __restrict__ outg) {
    __shared__ float tg[8 * 12 * 12];   // 1152
    __shared__ float gk[125];
    int bid = blockIdx.x;
    int xt = bid & 3, yt = (bid >> 2) & 3, zt = (bid >> 4) & 7, b = bid >> 7;
    int tid = threadIdx.x;
    if (tid < 125) gk[tid] = gaus_w[tid];   // replicated kernel: [0][0] slice
    const float* Ds = Dsum + b * DVOL;
    for (int i = tid; i < 1152; i += 256) {
        int lx = i % 12; int r = i / 12; int ly = r % 12; int lz = r / 12;
        int gz = zt * 4 - 2 + lz, gy = yt * 8 - 2 + ly, gx = xt * 8 - 2 + lx;
        float v = 0.f;
        if ((unsigned)gz < DN && (unsigned)gy < DN && (unsigned)gx < DN)
            v = Ds[(gz * DN + gy) * DN + gx];
        tg[i] = v;
    }
    __syncthreads();
    int px = tid & 7, py = (tid >> 3) & 7, pz = tid >> 6;
    const float inv31 = 1.f / 31.f;
    float zb = (float)(zt * 4 + pz - 2);
    float yb = (float)(yt * 8 + py - 2);
    float xb = (float)(xt * 8 + px - 2);
    float p = 0.f, a0 = 0.f, a1 = 0.f, a2 = 0.f;
    for (int tz = 0; tz < 5; ++tz)
    for (int ty = 0; ty < 5; ++ty) {
        int base = ((pz + tz) * 12 + py + ty) * 12 + px;
        #pragma unroll
        for (int tx = 0; tx < 5; ++tx) {
            float g = gk[tz * 25 + ty * 5 + tx];
            float v = g * tg[base + tx];
            p += v;
            a0 = fmaf(v, (zb + (float)tz) * inv31, a0);
            a1 = fmaf(v, (yb + (float)ty) * inv31, a1);
            a2 = fmaf(v, (xb + (float)tx) * inv31, a2);
        }
    }
    float denom = p + 1e-6f;
    float f0 = fminf(fmaxf(a0 / denom * 2.f - 1.f, -1.f), 1.f);
    float f1 = fminf(fmaxf(a1 / denom * 2.f - 1.f, -1.f), 1.f);
    float f2 = fminf(fmaxf(a2 / denom * 2.f - 1.f, -1.f), 1.f);
    int sp = ((zt * 4 + pz) * DN + yt * 8 + py) * DN + xt * 8 + px;
    filt[(b * 3 + 0) * DVOL + sp] = f0;
    filt[(b * 3 + 1) * DVOL + sp] = f1;
    filt[(b * 3 + 2) * DVOL + sp] = f2;
    outg[(size_t)(b * DVOL + sp) * 3 + 0] = f0;
    outg[(size_t)(b * DVOL + sp) * 3 + 1] = f1;
    outg[(size_t)(b * DVOL + sp) * 3 + 2] = f2;
}

// ---- K3: trilinear grid sample. 8192 blocks x 128 thr; tile (2z,4y,16x),
// 2 channels per block -> 64 waves/CU oversubscription (TLP latency hiding).
__global__ __launch_bounds__(128) void k_sample(const float* __restrict__ x,
                                                const float* __restrict__ filt,
                                                float* __restrict__ y) {
    int bid = blockIdx.x;
    int wid = (bid & 7) * 1024 + (bid >> 3);  // 8192%8==0, bijective chunk
    int xt = wid & 1;
    int yt = (wid >> 1) & 7;
    int zt = (wid >> 4) & 15;
    int cgrp = (wid >> 8) & 15;               // 16 groups x 2 channels
    int b  = wid >> 12;
    int tid = threadIdx.x;
    int px = tid & 15, py = (tid >> 4) & 3, pz = tid >> 6;
    int sp = ((zt * 2 + pz) * DN + yt * 4 + py) * DN + xt * 16 + px;
    const float* fb = filt + b * 3 * DVOL;
    float g0 = fb[sp], g1 = fb[DVOL + sp], g2 = fb[2 * DVOL + sp];

    float ix = ((g0 + 1.0f) * (float)XN - 1.0f) * 0.5f;
    float iy = ((g1 + 1.0f) * (float)XN - 1.0f) * 0.5f;
    float iz = ((g2 + 1.0f) * (float)XN - 1.0f) * 0.5f;
    float x0f = floorf(ix), y0f = floorf(iy), z0f = floorf(iz);
    float wx = ix - x0f, wyf = iy - y0f, wz = iz - z0f;
    int x0 = (int)x0f, y0i = (int)y0f, z0 = (int)z0f;

    int offs[8];
    float wts[8];
    #pragma unroll
    for (int t = 0; t < 8; ++t) {
        int dz = t >> 2, dy = (t >> 1) & 1, dx = t & 1;
        int zc = z0 + dz, yc = y0i + dy, xc = x0 + dx;
        bool valid = (unsigned)zc < (unsigned)XN && (unsigned)yc < (unsigned)XN &&
                     (unsigned)xc < (unsigned)XN;
        int zcl = min(max(zc, 0), XN - 1);
        int ycl = min(max(yc, 0), XN - 1);
        int xcl = min(max(xc, 0), XN - 1);
        offs[t] = zcl * (XN * XN) + ycl * XN + xcl;
        float w = (dz ? wz : 1.f - wz) * (dy ? wyf : 1.f - wyf) * (dx ? wx : 1.f - wx);
        wts[t] = valid ? w : 0.f;
    }

    const float* xc0 = x + (size_t)(b * C + cgrp * 2) * XVOL;
    float t0[8], t1[8];
    #pragma unroll
    for (int k = 0; k < 8; ++k) t0[k] = xc0[offs[k]];
    #pragma unroll
    for (int k = 0; k < 8; ++k) t1[k] = xc0[XVOL + offs[k]];

    float a0 = 0.f, a1 = 0.f;
    #pragma unroll
    for (int k = 0; k < 8; ++k) a0 = fmaf(wts[k], t0[k], a0);
    #pragma unroll
    for (int k = 0; k < 8; ++k) a1 = fmaf(wts[k], t1[k], a1);
    y[(size_t)(b * C + cgrp * 2 + 0) * DVOL + sp] = a0;
    y[(size_t)(b * C + cgrp * 2 + 1) * DVOL + sp] = a1;
}

extern "C" void kernel_launch(void* const* d_in, const int* in_sizes, int n_in,
                              void* d_out, int out_size, void* d_ws, size_t ws_size,
                              hipStream_t stream) {
    const float* x      = (const float*)d_in[0];
    const float* conv_w = (const float*)d_in[1];
    const float* conv_b = (const float*)d_in[2];
    const float* gaus_w = (const float*)d_in[3];

    float* out = (float*)d_out;
    float* y_out = out;
    float* D_out = out + (size_t)2097152;
    float* g_out = out + (size_t)4194304;

    float* ws   = (float*)d_ws;
    float* Dsum = ws;                         // 65536 f
    float* filt = ws + 65536;                 // 196608 f
    float* wsum = ws + 262144;                // 2049 f (+pad to 2112)
    unsigned short* wfrag = (unsigned short*)(ws + 264256);  // 65536 u16

    k_prep<<<dim3(512), dim3(256), 0, stream>>>(conv_w, conv_b, wfrag, wsum);
    k_conv_mfma<<<dim3(1024), dim3(256), 0, stream>>>(x, wfrag, wsum, conv_b,
                                                      D_out, Dsum);
    k_gauss<<<dim3(256), dim3(256), 0, stream>>>(Dsum, gaus_w, filt, g_out);
    k_sample<<<dim3(8192), dim3(128), 0, stream>>>(x, filt, y_out);
    (void)in_sizes; (void)n_in; (void)out_size; (void)ws_size;
}

// Round 16
// 84.537 us; speedup vs baseline: 1.2331x; 1.0360x over previous
//
#include <hip/hip_runtime.h>
#include <hip/hip_bf16.h>

// ---------------------------------------------------------------------------
// Def_DownSampling, round 16.
//  * gaus_w identical per (oc,ic) => gaussian path uses channel-summed field.
//  * conv3+avgpool folded to stride-2 4^3 conv (W4), exact algebra.
//  * D via bf16 MFMA; Dsum kept fp32 (packed dot) for the grid path.
//  * R16: conv taps staged to a zero-padded fp32 LDS tile (R4's proven
//    staging/read code) -> kills the 40-FMA/lane shmask bill; weights keep
//    R13/R15's LDS double-buffer. Unroll-2 pipeline, no register copies,
//    1 barrier/ic. Tap values bit-identical to R15 (exact 0/1 selections).
// Outputs: y (2,32,32,32,32) | D (2,32,32,32,32) | grid-mean (2,32,32,32,3)
// ---------------------------------------------------------------------------

#define XN 64
#define DN 32
#define C  32
#define XVOL (XN * XN * XN)   // 262144
#define DVOL (DN * DN * DN)   // 32768

typedef __attribute__((ext_vector_type(8))) short short8v;
typedef __attribute__((ext_vector_type(4))) float float4v;

struct __attribute__((packed, aligned(4))) f4u { float4v v; };
struct __attribute__((packed, aligned(4))) s8u { short8v v; };

static __device__ __forceinline__ short f2bf(float f) {
    union { float f; unsigned u; } v; v.f = f;
    unsigned r = (v.u + 0x7fffu + ((v.u >> 16) & 1u)) >> 16;   // RNE
    return (short)r;
}

static __device__ __forceinline__ unsigned pk2(float a, float b) {
    __hip_bfloat162 h = __float22bfloat162_rn(float2{a, b});
    union { __hip_bfloat162 h2; unsigned u; } cv; cv.h2 = h;
    return cv.u;
}

// W4[ic][u][oc] = (1/8) sum_{s in {0,1}^3} conv_w[oc][ic][u-s]
static __device__ __forceinline__ float w4val(const float* __restrict__ conv_w,
                                              int ic, int u, int oc) {
    int uz = u >> 4, uy = (u >> 2) & 3, ux = u & 3;
    float s = 0.f;
    #pragma unroll
    for (int sz = 0; sz < 2; ++sz) {
        int tz = uz - sz; if (tz < 0 || tz > 2) continue;
        #pragma unroll
        for (int sy = 0; sy < 2; ++sy) {
            int ty = uy - sy; if (ty < 0 || ty > 2) continue;
            #pragma unroll
            for (int sx = 0; sx < 2; ++sx) {
                int tx = ux - sx; if (tx < 0 || tx > 2) continue;
                s += conv_w[(oc * C + ic) * 27 + tz * 9 + ty * 3 + tx];
            }
        }
    }
    return 0.125f * s;
}

// ---- K0: blocks 0..255 pack A-fragments (bf16) + biassum;
//          blocks 256..511 compute wsum[k] = sum_oc W4[k][oc] via shfl tree.
__global__ __launch_bounds__(256) void k_prep(const float* __restrict__ conv_w,
                                              const float* __restrict__ conv_b,
                                              unsigned short* __restrict__ wfrag,
                                              float* __restrict__ wsum) {
    int bid = blockIdx.x;
    int tid = threadIdx.x;
    if (bid < 256) {
        int i = bid * 256 + tid;                // 65536
        int e = i & 7;
        int l = (i >> 3) & 63;
        int sf = i >> 9;
        int f = sf & 1, step = sf >> 1;
        int oc = f * 16 + (l & 15);
        int k = step * 32 + ((l >> 4) * 8 + e);
        float v = w4val(conv_w, k >> 6, k & 63, oc);
        wfrag[i] = (unsigned short)f2bf(v);
        if (i == 0) {
            float s = 0.f;
            for (int o = 0; o < C; ++o) s += conv_b[o];
            wsum[2048] = s;
        }
    } else {
        int i2 = (bid - 256) * 256 + tid;       // 65536 = 2048 k x 32 oc
        int oc = tid & 31;
        int kk = i2 >> 5;
        float v = w4val(conv_w, kk >> 6, kk & 63, oc);
        v += __shfl_xor(v, 1, 64);
        v += __shfl_xor(v, 2, 64);
        v += __shfl_xor(v, 4, 64);
        v += __shfl_xor(v, 8, 64);
        v += __shfl_xor(v, 16, 64);
        if (oc == 0) wsum[kk] = v;
    }
}

// ---- K1: MFMA conv. 1024 blocks x 256 thr (4 waves).
// Wave w = output (zt*2+(w>>1), yt*2+(w&1), xt*16 + col), all 32 oc.
// Taps: zero-padded fp32 LDS tile 6x6x34 (stride 36), double-buffered per ic.
// Weights: LDS double-buffer, 2 ic (8 KB) per stage (R13/R15 pattern).
#define NSTG (6 * 6 * 34)     // 1224 staged floats per ic
#define TILEF (6 * 6 * 36)    // 1296 with row padding

__global__ __launch_bounds__(256) void k_conv_mfma(
        const float* __restrict__ x, const unsigned short* __restrict__ wfrag,
        const float* __restrict__ wsum, const float* __restrict__ bias,
        float* __restrict__ Dout, float* __restrict__ Dsum) {
    __shared__ float wsl[2112];
    __shared__ char wbuf[2 * 8320];
    __shared__ float tile[2][TILEF];
    int tid = threadIdx.x;
    for (int i = tid; i < 513; i += 256)
        *(float4v*)&wsl[i * 4] = *(const float4v*)&wsum[i * 4];

    int bid = blockIdx.x;
    int wid = (bid & 7) * 128 + (bid >> 3);      // XCD-chunked swizzle (1024%8==0)
    int xt = wid & 1;
    int yt = (wid >> 1) & 15;
    int zt = (wid >> 5) & 15;
    int b  = wid >> 9;
    int w = tid >> 6, lane = tid & 63;
    int col = lane & 15, g = lane >> 4;
    int wpz = w >> 1, wpy = w & 1;
    int pz = zt * 2 + wpz, py = yt * 2 + wpy, px = xt * 16 + col;

    const float* xb = x + (size_t)b * C * XVOL;
    const char* wfb = (const char*)wfrag;
    int wsdst = (tid >> 6) * 1040 + (tid & 63) * 16;

    // hoisted tap-staging index math (ic-invariant): i = tid + it*256 < 1224
    int gz0 = zt * 4 - 1, gy0 = yt * 4 - 1, gx0 = xt * 32 - 1;
    int  soff[5], sdst[5];
    bool sval[5], swr[5];
    #pragma unroll
    for (int it = 0; it < 5; ++it) {
        int i = tid + it * 256;
        int lx = i % 34; int r = i / 34; int ly = r % 6; int lz = r / 6;
        int gz = gz0 + lz, gy = gy0 + ly, gx = gx0 + lx;
        bool inr = i < NSTG;
        swr[it]  = inr;
        sval[it] = inr && (unsigned)gz < XN && (unsigned)gy < XN && (unsigned)gx < XN;
        soff[it] = ((gz & 63) * XN + (gy & 63)) * XN + (gx & 63);
        sdst[it] = inr ? (lz * 6 + ly) * 36 + lx : 0;
    }

    // per-lane LDS read base: z part (2wpz + g>>1), y part 2wpy + (g&1)*2
    int base_g = ((2 * wpz + (g >> 1)) * 6 + 2 * wpy + (g & 1) * 2) * 36 + 2 * col;

    float4v acc0 = {0.f, 0.f, 0.f, 0.f};
    float4v acc1 = {0.f, 0.f, 0.f, 0.f};
    float4v dpv = {0.f, 0.f, 0.f, 0.f};
    float svA[5], svB[5];
    short8v sg0, sg1;

#define TLOAD(SV, j) do {                                                    \
    const float* xp = xb + (size_t)(j) * XVOL;                               \
    _Pragma("unroll")                                                        \
    for (int it = 0; it < 5; ++it)                                           \
        SV[it] = sval[it] ? xp[soff[it]] : 0.f;                              \
} while (0)

#define TWRITE(dst, SV) do {                                                 \
    _Pragma("unroll")                                                        \
    for (int it = 0; it < 5; ++it)                                           \
        if (swr[it]) (dst)[sdst[it]] = SV[it];                               \
} while (0)

#define WLOAD(st) do {                                                       \
    const char* wp = wfb + (size_t)(st) * 8192 + tid * 16;                   \
    sg0 = ((const s8u*)(wp))->v;                                             \
    sg1 = ((const s8u*)(wp + 4096))->v;                                      \
} while (0)

#define WWRITE(bf) do {                                                      \
    *(short8v*)(wbuf + (bf) * 8320 + wsdst) = sg0;                           \
    *(short8v*)(wbuf + (bf) * 8320 + 4160 + wsdst) = sg1;                    \
} while (0)

#define COMPT(ic) do {                                                       \
    const float* t = tile[(ic) & 1];                                         \
    _Pragma("unroll")                                                        \
    for (int h5 = 0; h5 < 2; ++h5) {                                         \
        int off0 = base_g + h5 * 432;                                        \
        float2 v01 = *(const float2*)&t[off0];                               \
        float2 v23 = *(const float2*)&t[off0 + 2];                           \
        float2 v45 = *(const float2*)&t[off0 + 36];                          \
        float2 v67 = *(const float2*)&t[off0 + 38];                          \
        float4v r0 = {v01.x, v01.y, v23.x, v23.y};                           \
        float4v r1 = {v45.x, v45.y, v67.x, v67.y};                           \
        const float4v wlo = *(const float4v*)&wsl[((ic) * 2 + h5) * 32 + g * 8];     \
        const float4v whi = *(const float4v*)&wsl[((ic) * 2 + h5) * 32 + g * 8 + 4]; \
        dpv += wlo * r0;                                                     \
        dpv += whi * r1;                                                     \
        union { short8v s; unsigned u[4]; } Bv;                              \
        Bv.u[0] = pk2(r0[0], r0[1]); Bv.u[1] = pk2(r0[2], r0[3]);            \
        Bv.u[2] = pk2(r1[0], r1[1]); Bv.u[3] = pk2(r1[2], r1[3]);            \
        const char* wl = wbuf + (((ic) >> 1) & 1) * 8320 + ((ic) & 1) * 4160 \
                         + lane * 16;                                        \
        short8v w0 = *(const short8v*)(wl + (h5 * 2) * 1040);                \
        short8v w1 = *(const short8v*)(wl + (h5 * 2 + 1) * 1040);            \
        acc0 = __builtin_amdgcn_mfma_f32_16x16x32_bf16(w0, Bv.s, acc0, 0, 0, 0); \
        acc1 = __builtin_amdgcn_mfma_f32_16x16x32_bf16(w1, Bv.s, acc1, 0, 0, 0); \
    }                                                                        \
} while (0)

    // prologue: weights group 0; taps ic0 staged, ic1 in regs
    WLOAD(0);
    WWRITE(0);
    {
        float sv[5];
        TLOAD(sv, 0);
        TWRITE(tile[0], sv);
    }
    TLOAD(svB, 1);
    __syncthreads();

    for (int st = 0; st < 16; ++st) {
        int ic0 = 2 * st, ic1 = 2 * st + 1;
        // even ic body
        if (st > 0) __syncthreads();
        TWRITE(tile[1], svB);                 // taps for ic1
        if (ic0 + 2 < C) TLOAD(svA, ic0 + 2);
        if (st < 15) WLOAD(st + 1);           // weights group st+1 (issue-early)
        COMPT(ic0);
        // odd ic body
        __syncthreads();
        if (ic0 + 2 < C) TWRITE(tile[0], svA);
        if (ic1 + 2 < C) TLOAD(svB, ic1 + 2);
        COMPT(ic1);
        if (st < 15) WWRITE((st + 1) & 1);    // write-late (2 barriers since readers)
    }

#undef TLOAD
#undef TWRITE
#undef WLOAD
#undef WWRITE
#undef COMPT

    float dp = (dpv[0] + dpv[1]) + (dpv[2] + dpv[3]);
    dp += __shfl_xor(dp, 16, 64);
    dp += __shfl_xor(dp, 32, 64);

    int sp = pz * (DN * DN) + py * DN + px;
    float4v b0 = *(const float4v*)&bias[g * 4];
    float4v b1 = *(const float4v*)&bias[16 + g * 4];
    #pragma unroll
    for (int r = 0; r < 4; ++r) {
        int oc0 = g * 4 + r;
        int oc1 = 16 + g * 4 + r;
        Dout[(size_t)(b * C + oc0) * DVOL + sp] = acc0[r] + b0[r];
        Dout[(size_t)(b * C + oc1) * DVOL + sp] = acc1[r] + b1[r];
    }
    if (g == 0)
        Dsum[b * DVOL + sp] = dp + wsl[2048];
}

// ---- K2: 5^3 gaussian, LDS-staged. Block = (4z x 8y x 8x), 256 blocks.
__global__ __launch_bounds__(256) void k_gauss(const float* __restrict__ Dsum,
                                               const float* __restrict__ gaus_w,
                                               float* __restrict__ filt,
                                               float* __restrict__ outg) {
    __shared__ float tg[8 * 12 * 12];   // 1152
    __shared__ float gk[125];
    int bid = blockIdx.x;
    int xt = bid & 3, yt = (bid >> 2) & 3, zt = (bid >> 4) & 7, b = bid >> 7;
    int tid = threadIdx.x;
    if (tid < 125) gk[tid] = gaus_w[tid];   // replicated kernel: [0][0] slice
    const float* Ds = Dsum + b * DVOL;
    for (int i = tid; i < 1152; i += 256) {
        int lx = i % 12; int r = i / 12; int ly = r % 12; int lz = r / 12;
        int gz = zt * 4 - 2 + lz, gy = yt * 8 - 2 + ly, gx = xt * 8 - 2 + lx;
        float v = 0.f;
        if ((unsigned)gz < DN && (unsigned)gy < DN && (unsigned)gx < DN)
            v = Ds[(gz * DN + gy) * DN + gx];
        tg[i] = v;
    }
    __syncthreads();
    int px = tid & 7, py = (tid >> 3) & 7, pz = tid >> 6;
    const float inv31 = 1.f / 31.f;
    float zb = (float)(zt * 4 + pz - 2);
    float yb = (float)(yt * 8 + py - 2);
    float xb = (float)(xt * 8 + px - 2);
    float p = 0.f, a0 = 0.f, a1 = 0.f, a2 = 0.f;
    for (int tz = 0; tz < 5; ++tz)
    for (int ty = 0; ty < 5; ++ty) {
        int base = ((pz + tz) * 12 + py + ty) * 12 + px;
        #pragma unroll
        for (int tx = 0; tx < 5; ++tx) {
            float g = gk[tz * 25 + ty * 5 + tx];
            float v = g * tg[base + tx];
            p += v;
            a0 = fmaf(v, (zb + (float)tz) * inv31, a0);
            a1 = fmaf(v, (yb + (float)ty) * inv31, a1);
            a2 = fmaf(v, (xb + (float)tx) * inv31, a2);
        }
    }
    float denom = p + 1e-6f;
    float f0 = fminf(fmaxf(a0 / denom * 2.f - 1.f, -1.f), 1.f);
    float f1 = fminf(fmaxf(a1 / denom * 2.f - 1.f, -1.f), 1.f);
    float f2 = fminf(fmaxf(a2 / denom * 2.f - 1.f, -1.f), 1.f);
    int sp = ((zt * 4 + pz) * DN + yt * 8 + py) * DN + xt * 8 + px;
    filt[(b * 3 + 0) * DVOL + sp] = f0;
    filt[(b * 3 + 1) * DVOL + sp] = f1;
    filt[(b * 3 + 2) * DVOL + sp] = f2;
    outg[(size_t)(b * DVOL + sp) * 3 + 0] = f0;
    outg[(size_t)(b * DVOL + sp) * 3 + 1] = f1;
    outg[(size_t)(b * DVOL + sp) * 3 + 2] = f2;
}

// ---- K3: trilinear grid sample. 8192 blocks x 128 thr; tile (2z,4y,16x),
// 2 channels per block -> 64 waves/CU oversubscription (TLP latency hiding).
__global__ __launch_bounds__(128) void k_sample(const float* __restrict__ x,
                                                const float* __restrict__ filt,
                                                float* __restrict__ y) {
    int bid = blockIdx.x;
    int wid = (bid & 7) * 1024 + (bid >> 3);  // 8192%8==0, bijective chunk
    int xt = wid & 1;
    int yt = (wid >> 1) & 7;
    int zt = (wid >> 4) & 15;
    int cgrp = (wid >> 8) & 15;               // 16 groups x 2 channels
    int b  = wid >> 12;
    int tid = threadIdx.x;
    int px = tid & 15, py = (tid >> 4) & 3, pz = tid >> 6;
    int sp = ((zt * 2 + pz) * DN + yt * 4 + py) * DN + xt * 16 + px;
    const float* fb = filt + b * 3 * DVOL;
    float g0 = fb[sp], g1 = fb[DVOL + sp], g2 = fb[2 * DVOL + sp];

    float ix = ((g0 + 1.0f) * (float)XN - 1.0f) * 0.5f;
    float iy = ((g1 + 1.0f) * (float)XN - 1.0f) * 0.5f;
    float iz = ((g2 + 1.0f) * (float)XN - 1.0f) * 0.5f;
    float x0f = floorf(ix), y0f = floorf(iy), z0f = floorf(iz);
    float wx = ix - x0f, wyf = iy - y0f, wz = iz - z0f;
    int x0 = (int)x0f, y0i = (int)y0f, z0 = (int)z0f;

    int offs[8];
    float wts[8];
    #pragma unroll
    for (int t = 0; t < 8; ++t) {
        int dz = t >> 2, dy = (t >> 1) & 1, dx = t & 1;
        int zc = z0 + dz, yc = y0i + dy, xc = x0 + dx;
        bool valid = (unsigned)zc < (unsigned)XN && (unsigned)yc < (unsigned)XN &&
                     (unsigned)xc < (unsigned)XN;
        int zcl = min(max(zc, 0), XN - 1);
        int ycl = min(max(yc, 0), XN - 1);
        int xcl = min(max(xc, 0), XN - 1);
        offs[t] = zcl * (XN * XN) + ycl * XN + xcl;
        float w = (dz ? wz : 1.f - wz) * (dy ? wyf : 1.f - wyf) * (dx ? wx : 1.f - wx);
        wts[t] = valid ? w : 0.f;
    }

    const float* xc0 = x + (size_t)(b * C + cgrp * 2) * XVOL;
    float t0[8], t1[8];
    #pragma unroll
    for (int k = 0; k < 8; ++k) t0[k] = xc0[offs[k]];
    #pragma unroll
    for (int k = 0; k < 8; ++k) t1[k] = xc0[XVOL + offs[k]];

    float a0 = 0.f, a1 = 0.f;
    #pragma unroll
    for (int k = 0; k < 8; ++k) a0 = fmaf(wts[k], t0[k], a0);
    #pragma unroll
    for (int k = 0; k < 8; ++k) a1 = fmaf(wts[k], t1[k], a1);
    y[(size_t)(b * C + cgrp * 2 + 0) * DVOL + sp] = a0;
    y[(size_t)(b * C + cgrp * 2 + 1) * DVOL + sp] = a1;
}

extern "C" void kernel_launch(void* const* d_in, const int* in_sizes, int n_in,
                              void* d_out, int out_size, void* d_ws, size_t ws_size,
                              hipStream_t stream) {
    const float* x      = (const float*)d_in[0];
    const float* conv_w = (const float*)d_in[1];
    const float* conv_b = (const float*)d_in[2];
    const float* gaus_w = (const float*)d_in[3];

    float* out = (float*)d_out;
    float* y_out = out;
    float* D_out = out + (size_t)2097152;
    float* g_out = out + (size_t)4194304;

    float* ws   = (float*)d_ws;
    float* Dsum = ws;                         // 65536 f
    float* filt = ws + 65536;                 // 196608 f
    float* wsum = ws + 262144;                // 2049 f (+pad to 2112)
    unsigned short* wfrag = (unsigned short*)(ws + 264256);  // 65536 u16

    k_prep<<<dim3(512), dim3(256), 0, stream>>>(conv_w, conv_b, wfrag, wsum);
    k_conv_mfma<<<dim3(1024), dim3(256), 0, stream>>>(x, wfrag, wsum, conv_b,
                                                      D_out, Dsum);
    k_gauss<<<dim3(256), dim3(256), 0, stream>>>(Dsum, gaus_w, filt, g_out);
    k_sample<<<dim3(8192), dim3(128), 0, stream>>>(x, filt, y_out);
    (void)in_sizes; (void)n_in; (void)out_size; (void)ws_size;
}